// Round 8
// baseline (46759.082 us; speedup 1.0000x reference)
//
#include <hip/hip_runtime.h>
#include <cstddef>

#define DEV __device__ __forceinline__

// ---- dims: B=16 S=256 IN_DIM=264 H=512 4H=2048 XI=471 N=256 M=64 R=4 OUT=256
constexpr int S_ = 256;
constexpr int NB = 256;
constexpr int NT = 256;

// R7 post-mortem: per-step cost invariant to barrier protocol AND epoch count
// -> dominated by ~30 serial LLC round trips (sys sc0sc1) on the critical path.
// R8: (a) fuse LSTM+xi+ctrl+content into ONE XCD-pinned block per batch (kills
// the xi-crew flag chain + XI buffer); (b) re-place link blocks (bid=16*rc+b)
// so the ENTIRE per-batch dataflow is same-XCD -> agent scope (local L2,
// ~300ns) instead of sys (LLC, ~1.5-2.5us). Cross-XCD only: H/RV/GP/YH (sys)
// and BWD (sys zero + device atomicAdd + sys read, R7-proven combo).
constexpr size_t OFF_H    = 0;         // 16x512   [sys]
constexpr size_t OFF_C    = 8192;      // 16x512   [private: batch block b]
constexpr size_t OFF_MEM  = 24576;     // 16x256x64 [agent, XCD b%8]
constexpr size_t OFF_NRM  = 286720;    // 16x256   [agent]
constexpr size_t OFF_USG  = 290816;    // 16x256   [private: batch block b]
constexpr size_t OFF_LNK  = 294912;    // 16x256x256 [private: link block 16rc+b]
constexpr size_t OFF_PRC  = 1343488;   // 2x16x256 [agent]
constexpr size_t OFF_WR   = 1351680;   // 16x4x256 [agent]
constexpr size_t OFF_WW   = 1368064;   // 16x256   [agent]
constexpr size_t OFF_RV   = 1372160;   // 16x256   [sys]
constexpr size_t OFF_KNR  = 1383936;   // 16x256   [agent]
constexpr size_t OFF_PI   = 1388032;   // 16x16    [agent]
constexpr size_t OFF_ERS  = 1388288;   // 16x64    [agent]
constexpr size_t OFF_WVC  = 1389312;   // 16x64    [agent]
constexpr size_t OFF_FWD  = 1390336;   // 16x4x256 [agent]
constexpr size_t OFF_BWD  = 1406720;   // 16x4x256 [sys zero + dev atomicAdd + sys read]
constexpr size_t OFF_ALC  = 1423104;   // 16x256   [agent]
constexpr size_t OFF_CW   = 1427200;   // 16x256   [agent]
constexpr size_t OFF_SCL  = 1431296;   // 16x4     [agent]
constexpr size_t OFF_GPA  = 1431360;   // 16x2048 gate partials ping (t even) [sys+atomic]
constexpr size_t OFF_GPB  = 1464128;   // 16x2048 gate partials pong (t odd)
constexpr size_t OFF_YH   = 1496896;   // 16x256   [sys]
constexpr size_t OFF_HFL  = 1500992;   // 16 h-flags, 1/128B line
constexpr size_t OFF_FLG  = 1501536;   // 256 arrival flags, 1/128B line
constexpr size_t OFF_REL  = 1509728;   // 16 replicated release lines
constexpr size_t WS_TOTAL = 1510240;   // ~6.04 MB

typedef unsigned long long u64_;
union F2U { u64_ u; float2 f; };
DEV float2 ld2_sys(const float* p){ F2U c; c.u=__hip_atomic_load((const u64_*)p,__ATOMIC_RELAXED,__HIP_MEMORY_SCOPE_SYSTEM); return c.f; }
DEV void   st2_sys(float* p, float2 v){ F2U c; c.f=v; __hip_atomic_store((u64_*)p,c.u,__ATOMIC_RELAXED,__HIP_MEMORY_SCOPE_SYSTEM); }
DEV float2 ld2_agt(const float* p){ F2U c; c.u=__hip_atomic_load((const u64_*)p,__ATOMIC_RELAXED,__HIP_MEMORY_SCOPE_AGENT); return c.f; }
DEV void   st2_agt(float* p, float2 v){ F2U c; c.f=v; __hip_atomic_store((u64_*)p,c.u,__ATOMIC_RELAXED,__HIP_MEMORY_SCOPE_AGENT); }
DEV float  ld_sys(const float* p){ return __hip_atomic_load((float*)p,__ATOMIC_RELAXED,__HIP_MEMORY_SCOPE_SYSTEM); }
DEV void   st_sys(float* p,float v){ __hip_atomic_store(p,v,__ATOMIC_RELAXED,__HIP_MEMORY_SCOPE_SYSTEM); }
DEV float  ld_agt(const float* p){ return __hip_atomic_load((float*)p,__ATOMIC_RELAXED,__HIP_MEMORY_SCOPE_AGENT); }
DEV void   st_agt(float* p,float v){ __hip_atomic_store(p,v,__ATOMIC_RELAXED,__HIP_MEMORY_SCOPE_AGENT); }

DEV float sigm(float x){ return 1.0f/(1.0f+expf(-x)); }
DEV float oneplus_(float x){ float sp = (x>20.0f)? x : log1pf(expf(x)); return 1.0f+sp; }

DEV float wredsum(float v){
  #pragma unroll
  for (int o=32;o>0;o>>=1) v += __shfl_xor(v,o);
  return v;
}
DEV float hredsum32(float v){
  #pragma unroll
  for (int o=16;o>0;o>>=1) v += __shfl_xor(v,o);
  return v;
}
DEV float wredmax(float v){
  #pragma unroll
  for (int o=32;o>0;o>>=1) v = fmaxf(v,__shfl_xor(v,o));
  return v;
}
DEV float bredsum(float v, float* red){
  v = wredsum(v);
  if ((threadIdx.x&63)==0) red[threadIdx.x>>6]=v;
  __syncthreads();
  float r = red[0]+red[1]+red[2]+red[3];
  __syncthreads();
  return r;
}
DEV float bredmax(float v, float* red){
  v = wredmax(v);
  if ((threadIdx.x&63)==0) red[threadIdx.x>>6]=v;
  __syncthreads();
  float r = fmaxf(fmaxf(red[0],red[1]),fmaxf(red[2],red[3]));
  __syncthreads();
  return r;
}

// Fence-free grid barrier (R4..R7-proven). Master = block NB-1 (idle).
DEV void gbar(unsigned* flg, unsigned* rel, unsigned ep, int bid){
  __syncthreads();
  const int tid = threadIdx.x;
  if (bid == NB-1){
    if (tid == 0)
      __hip_atomic_store(flg + (size_t)(NB-1)*32, ep, __ATOMIC_RELAXED, __HIP_MEMORY_SCOPE_SYSTEM);
    if (tid < 64){
      bool ok;
      do {
        ok = true;
        #pragma unroll
        for (int s=0;s<4;++s){
          unsigned v = __hip_atomic_load(flg + (size_t)(tid + (s<<6))*32,
                                         __ATOMIC_RELAXED, __HIP_MEMORY_SCOPE_SYSTEM);
          ok = ok && (v >= ep);
        }
        if (!__all(ok)) __builtin_amdgcn_s_sleep(1);
      } while (!__all(ok));
      if (tid < 16)
        __hip_atomic_store(rel + (size_t)tid*32, ep,
                           __ATOMIC_RELAXED, __HIP_MEMORY_SCOPE_SYSTEM);
    }
  } else {
    if (tid == 0){
      __hip_atomic_store(flg + (size_t)bid*32, ep,
                         __ATOMIC_RELAXED, __HIP_MEMORY_SCOPE_SYSTEM);
      unsigned* myrel = rel + (size_t)(bid>>4)*32;
      while (__hip_atomic_load(myrel, __ATOMIC_RELAXED, __HIP_MEMORY_SCOPE_SYSTEM) < ep)
        __builtin_amdgcn_s_sleep(2);
    }
  }
  __syncthreads();
}

// wait for all 16 h-flags >= tgt (monotone in t)
DEV void wait_h16(unsigned* hfl, unsigned tgt){
  if (threadIdx.x < 64){
    int l = threadIdx.x;
    bool ok;
    do {
      unsigned v = (l<16) ? __hip_atomic_load(hfl + (size_t)l*32,
                      __ATOMIC_RELAXED, __HIP_MEMORY_SCOPE_SYSTEM) : tgt;
      ok = __all(v >= tgt);
      if (!ok) __builtin_amdgcn_s_sleep(1);
    } while (!ok);
  }
  __syncthreads();
}

// skinny GEMM: 32 cols x 16 batches, in-block 8-way ksplit. sx: LDS [k][20].
DEV void sgemm_core(float* sred, const float* sx, const float* __restrict__ W,
                    int ldw, int colx, int kn)
{
  const int tid = threadIdx.x;
  const int ks  = tid >> 5;
  const int k0  = ks * kn;
  float acc[16];
  #pragma unroll
  for (int i=0;i<16;++i) acc[i]=0.f;
  const float* wp = W + (size_t)k0*ldw + colx;
  const float* xp = sx + k0*20;
  #pragma unroll 4
  for (int k=0;k<kn;++k){
    float w = *wp; wp += ldw;
    float4 x0 = *(const float4*)(xp);
    float4 x1 = *(const float4*)(xp+4);
    float4 x2 = *(const float4*)(xp+8);
    float4 x3 = *(const float4*)(xp+12);
    xp += 20;
    acc[0]=fmaf(w,x0.x,acc[0]);  acc[1]=fmaf(w,x0.y,acc[1]);
    acc[2]=fmaf(w,x0.z,acc[2]);  acc[3]=fmaf(w,x0.w,acc[3]);
    acc[4]=fmaf(w,x1.x,acc[4]);  acc[5]=fmaf(w,x1.y,acc[5]);
    acc[6]=fmaf(w,x1.z,acc[6]);  acc[7]=fmaf(w,x1.w,acc[7]);
    acc[8]=fmaf(w,x2.x,acc[8]);  acc[9]=fmaf(w,x2.y,acc[9]);
    acc[10]=fmaf(w,x2.z,acc[10]); acc[11]=fmaf(w,x2.w,acc[11]);
    acc[12]=fmaf(w,x3.x,acc[12]); acc[13]=fmaf(w,x3.y,acc[13]);
    acc[14]=fmaf(w,x3.z,acc[14]); acc[15]=fmaf(w,x3.w,acc[15]);
  }
  const int col = tid & 31;
  #pragma unroll
  for (int b=0;b<16;++b) sred[ks*512 + b*32 + col] = acc[b];
}

#define SRED8(o) (sred[(o)]+sred[512+(o)]+sred[1024+(o)]+sred[1536+(o)]+ \
                  sred[2048+(o)]+sred[2560+(o)]+sred[3072+(o)]+sred[3584+(o)])

DEV void stage_x264(float* sx, const float* __restrict__ xin, int tt){
  for (int e=threadIdx.x; e<1056; e+=NT){
    int b = e/66, k4 = e - b*66;
    float4 v = *(const float4*)(xin + ((size_t)(b*256+tt))*264 + 4*k4);
    float* d = sx + (4*k4)*20 + b;
    d[0]=v.x; d[20]=v.y; d[40]=v.z; d[60]=v.w;
  }
}
DEV void stage_h_sys(float* sx, const float* h){
  #pragma unroll
  for (int i=0;i<16;++i){
    int e = threadIdx.x + (i<<8);
    int b = e>>8, k2 = e&255;
    float2 v = ld2_sys(h + (b<<9) + (k2<<1));
    float* d = sx + (k2*2)*20 + b;
    d[0]=v.x; d[20]=v.y;
  }
}
DEV void stage_rv_sys(float* sx, const float* rv){
  #pragma unroll
  for (int i=0;i<8;++i){
    int e = threadIdx.x + (i<<8);
    int b = e>>7, k2 = e&127;
    float2 v = ld2_sys(rv + (b<<8) + (k2<<1));
    float* d = sx + (k2*2)*20 + b;
    d[0]=v.x; d[20]=v.y;
  }
}

__global__ void k_zero(float* __restrict__ ws){
  size_t i = (size_t)blockIdx.x*blockDim.x + threadIdx.x;
  size_t st = (size_t)gridDim.x*blockDim.x;
  for (; i<WS_TOTAL; i+=st) ws[i]=0.0f;
}

__global__ __launch_bounds__(NT, 2) void k_dnc(
    const float* __restrict__ xin, const float* __restrict__ Wx,
    const float* __restrict__ Wh,  const float* __restrict__ bl,
    const float* __restrict__ Wxi, const float* __restrict__ bxi,
    const float* __restrict__ Wy,  const float* __restrict__ Wr,
    const float* __restrict__ by,  float* __restrict__ out,
    float* __restrict__ ws)
{
  __shared__ float smem[14336];
  float* sx   = smem;
  float* sred = smem + 10240;
  const int tid  = threadIdx.x;
  const int bid  = blockIdx.x;
  const int lane = tid & 63, wv = tid >> 6;
  const int half = lane >> 5, l32 = lane & 31;
  unsigned* flg = (unsigned*)(ws + OFF_FLG);
  unsigned* rel = (unsigned*)(ws + OFF_REL);
  unsigned* hfl = (unsigned*)(ws + OFF_HFL);
  unsigned ep = 0;

  // ---- prologue: gates-x(0) store-owned into GPA (h0=c0=rv0=0) ----
  if (bid >= 16 && bid < 80){
    stage_x264(sx, xin, 0);
    __syncthreads();
    int cbase = (bid-16)<<5;
    sgemm_core(sred, sx, Wx, 2048, cbase+(tid&31), 33);
    __syncthreads();
    for (int o=tid;o<512;o+=NT){
      int b=o>>5, c=o&31;
      st_sys(ws + OFF_GPA + (size_t)(b<<11) + cbase + c, SRED8(o));
    }
  }
  ep++; gbar(flg, rel, ep, bid);

  for (int t=0; t<S_; ++t){
    float* gp_cur = ws + ((t&1) ? OFF_GPB : OFF_GPA);
    float* gp_nxt = ws + ((t&1) ? OFF_GPA : OFF_GPB);

    // ====== P1: batch-blocks (LSTM+xi+ctrl+content) | gates-x/h crew | yh crew ======
    if (bid < 16){
      int b = bid;
      float* xv   = smem;          // 512
      float* shh  = smem + 512;    // 512
      float* uu   = smem + 1024;
      float* sa   = smem + 1280;
      float* sb   = smem + 1536;
      float* sims = smem + 1792;
      float* knw  = smem + 2048;   // 64
      float* red  = smem + 2112;   // 4
      // LSTM
      const float* gp = gp_cur + ((size_t)b<<11);
      int j2 = tid<<1;
      float2 gi = ld2_sys(gp + j2);
      float2 gf = ld2_sys(gp + 512 + j2);
      float2 gg = ld2_sys(gp + 1024 + j2);
      float2 go = ld2_sys(gp + 1536 + j2);
      float2 bi = *(const float2*)(bl + j2);
      float2 bf = *(const float2*)(bl + 512 + j2);
      float2 bg = *(const float2*)(bl + 1024 + j2);
      float2 bo = *(const float2*)(bl + 1536 + j2);
      float* cb = ws + OFF_C + (b<<9) + j2;
      float2 cc = *(float2*)cb;
      float2 cn, hn;
      cn.x = sigm(gf.x+bf.x)*cc.x + sigm(gi.x+bi.x)*tanhf(gg.x+bg.x);
      cn.y = sigm(gf.y+bf.y)*cc.y + sigm(gi.y+bi.y)*tanhf(gg.y+bg.y);
      hn.x = sigm(go.x+bo.x)*tanhf(cn.x);
      hn.y = sigm(go.y+bo.y)*tanhf(cn.y);
      *(float2*)cb = cn;
      st2_sys(ws + OFF_H + (b<<9) + j2, hn);
      shh[j2] = hn.x; shh[j2+1] = hn.y;
      { // zero bwd (sys; R7-proven combo with device atomicAdd)
        float2 z; z.x=0.f; z.y=0.f;
        float* bw = ws + OFF_BWD + ((size_t)b<<10);
        st2_sys(bw + (tid<<1), z);
        st2_sys(bw + 512 + (tid<<1), z);
      }
      __syncthreads();                       // drains h stores (vmcnt 0)
      if (tid==0)
        __hip_atomic_store(hfl + (size_t)b*32, (unsigned)(t+1),
                           __ATOMIC_RELAXED, __HIP_MEMORY_SCOPE_SYSTEM);
      // xi GEMM for this batch: h (LDS) x Wxi (L2-warm), 2 cols/thread
      {
        int c0 = tid;
        int c1 = (tid<215) ? tid+256 : 470;
        float a0 = bxi[c0], a1 = bxi[c1];
        const float* W0 = Wxi + c0;
        const float* W1 = Wxi + c1;
        #pragma unroll 4
        for (int k=0;k<512;++k){
          float hk = shh[k];
          a0 = fmaf(hk, W0[(size_t)k*471], a0);
          a1 = fmaf(hk, W1[(size_t)k*471], a1);
        }
        xv[c0] = a0;
        xv[c1] = a1;   // tid>=215 duplicate col 470 with identical value
      }
      __syncthreads();
      // ctrl
      int n = tid;
      float f0=sigm(xv[453]), f1=sigm(xv[454]), f2v=sigm(xv[455]), f3=sigm(xv[456]);
      const float* wrb = ws+OFF_WR+(size_t)(b<<10);
      float psi=(1.f-f0*ld_agt(wrb+n))*(1.f-f1*ld_agt(wrb+256+n))
               *(1.f-f2v*ld_agt(wrb+512+n))*(1.f-f3*ld_agt(wrb+768+n));
      float uo=ws[OFF_USG+(b<<8)+n];
      float wwp=ld_agt(ws+OFF_WW+(b<<8)+n);
      float un=(uo+wwp-uo*wwp)*psi;
      uu[n]=un; ws[OFF_USG+(b<<8)+n]=un;
      __syncthreads();
      int rk=0;
      #pragma unroll 8
      for (int j=0;j<256;++j){
        float uj=uu[j];
        rk += (uj<un)||(uj==un && j<n);
      }
      sa[rk]=un;
      __syncthreads();
      float* cur=sa; float* nxt=sb;
      for (int off=1;off<256;off<<=1){
        float v=cur[n]; if (n>=off) v*=cur[n-off];
        nxt[n]=v;
        __syncthreads();
        float* tmp=cur; cur=nxt; nxt=tmp;
      }
      float pe = rk ? cur[rk-1] : 1.f;
      float al = (1.f-un)*pe;
      st_agt(ws+OFF_ALC+(b<<8)+n, al);
      float sumA = bredsum(al, red);
      if (tid==0){
        st_agt(ws+OFF_SCL+b*4+0, sigm(xv[457]));
        st_agt(ws+OFF_SCL+b*4+1, sigm(xv[458]));
        st_agt(ws+OFF_SCL+b*4+2, sumA);
      }
      {
        int r=tid>>6, m=tid&63;
        float kv=xv[(r<<6)+m];
        float s2=wredsum(kv*kv);
        float br=oneplus_(xv[256+r]);
        st_agt(ws+OFF_KNR+(b<<8)+tid, kv*br/(sqrtf(s2)+1e-6f));
      }
      if (tid<4){
        float p0=xv[459+tid*3], p1=xv[460+tid*3], p2=xv[461+tid*3];
        float mx=fmaxf(p0,fmaxf(p1,p2));
        float e0=expf(p0-mx), e1=expf(p1-mx), e2=expf(p2-mx);
        float s=e0+e1+e2;
        st_agt(ws+OFF_PI+b*16+tid*3+0, e0/s);
        st_agt(ws+OFF_PI+b*16+tid*3+1, e1/s);
        st_agt(ws+OFF_PI+b*16+tid*3+2, e2/s);
      }
      if (tid<64){
        st_agt(ws+OFF_ERS+(b<<6)+tid, sigm(xv[325+tid]));
        st_agt(ws+OFF_WVC+(b<<6)+tid, xv[389+tid]);
      }
      // write-key content softmax (mem agent-local, same XCD)
      if (wv==0){
        float kv=xv[260+lane];
        float s2=wredsum(kv*kv);
        float bw_=oneplus_(xv[324]);
        knw[lane]=kv*bw_/(sqrtf(s2)+1e-6f);
      }
      __syncthreads();
      const float* memb=ws+OFF_MEM+(size_t)b*16384;
      for (int i=0;i<32;++i){
        int nn=(wv<<6)+(i<<1)+half;
        float2 v=ld2_agt(memb+(nn<<6)+(l32<<1));
        float d=hredsum32(v.x*knw[l32<<1]+v.y*knw[(l32<<1)+1]);
        if (l32==0) sims[nn]=d/(sqrtf(ld_agt(ws+OFF_NRM+(b<<8)+nn))+1e-6f);
      }
      __syncthreads();
      float s=sims[tid];
      float mx=bredmax(s,red); float e=expf(s-mx); float sm=bredsum(e,red);
      st_agt(ws+OFF_CW+(b<<8)+tid, e/sm);
    } else if (bid < 80){
      // gates-x(t+1) store-own, then gates-h(t+1) add (same cols, same block)
      if (t < 255){
        stage_x264(sx, xin, t+1);
        __syncthreads();
        int cbase = (bid-16)<<5;
        sgemm_core(sred, sx, Wx, 2048, cbase+(tid&31), 33);
        __syncthreads();
        float accv0 = SRED8(tid);
        float accv1 = SRED8(tid+256);
        wait_h16(hfl, (unsigned)(t+1));      // internal syncthreads orders sred reuse
        stage_h_sys(sx, ws+OFF_H);
        __syncthreads();
        sgemm_core(sred, sx, Wh, 2048, cbase+(tid&31), 64);
        __syncthreads();
        {
          int o=tid, b=o>>5, c=o&31;
          st_sys(gp_nxt + (size_t)(b<<11) + cbase + c, accv0 + SRED8(o));
          o=tid+256; b=o>>5; c=o&31;
          st_sys(gp_nxt + (size_t)(b<<11) + cbase + c, accv1 + SRED8(o));
        }
      }
    } else if (bid < 88){
      // yh GEMM
      wait_h16(hfl, (unsigned)(t+1));
      stage_h_sys(sx, ws+OFF_H);
      __syncthreads();
      int cbase = (bid-80)<<5;
      sgemm_core(sred, sx, Wy, 256, cbase+(tid&31), 64);
      __syncthreads();
      for (int o=tid;o<512;o+=NT){
        int b=o>>5, c=o&31;
        st_sys(ws + OFF_YH + (b<<8) + cbase + c, SRED8(o) + by[cbase+c]);
      }
    }
    ep++; gbar(flg, rel, ep, bid);

    // ====== P2: link+fwd/bwd (bid=16*rc+b, XCD-pinned) | mem update (128+b) ======
    if (bid < 128){
      int b=bid&15, rc=bid>>4;
      float* wwi=smem; float* wrl=smem+32; float* fpart=smem+160;
      float ga=ld_agt(ws+OFF_SCL+b*4), gw=ld_agt(ws+OFF_SCL+b*4+1);
      int j=tid;
      float wj=gw*(ga*ld_agt(ws+OFF_ALC+(b<<8)+j)+(1.f-ga)*ld_agt(ws+OFF_CW+(b<<8)+j));
      float pj=ld_agt(ws+OFF_PRC+(size_t)(t&1)*4096+(b<<8)+j);
      const float* wrb=ws+OFF_WR+(size_t)(b<<10);
      float wr0=ld_agt(wrb+j), wr1=ld_agt(wrb+256+j),
            wr2=ld_agt(wrb+512+j), wr3=ld_agt(wrb+768+j);
      if (tid<32){
        int i=(rc<<5)+tid;
        wwi[tid]=gw*(ga*ld_agt(ws+OFF_ALC+(b<<8)+i)+(1.f-ga)*ld_agt(ws+OFF_CW+(b<<8)+i));
      }
      if (tid<128) wrl[(tid>>5)*32+(tid&31)] = ld_agt(wrb+((tid>>5)<<8)+(rc<<5)+(tid&31));
      __syncthreads();
      float b0=0.f,b1=0.f,b2=0.f,b3=0.f;
      float* lrow=ws+OFF_LNK+(size_t)b*65536+(size_t)(rc<<5)*256;   // private, L2-warm
      for (int il=0;il<32;++il){
        int i=(rc<<5)+il;
        float Lo=lrow[il*256+j];
        float wi=wwi[il];
        float Ln=(1.f-wi-wj)*Lo + wi*pj;
        if (i==j) Ln=0.f;
        lrow[il*256+j]=Ln;
        float s0=wredsum(Ln*wr0), s1=wredsum(Ln*wr1), s2=wredsum(Ln*wr2), s3=wredsum(Ln*wr3);
        if (lane==0){
          fpart[wv*128+il]=s0; fpart[wv*128+32+il]=s1;
          fpart[wv*128+64+il]=s2; fpart[wv*128+96+il]=s3;
        }
        b0=fmaf(Ln,wrl[il],b0); b1=fmaf(Ln,wrl[32+il],b1);
        b2=fmaf(Ln,wrl[64+il],b2); b3=fmaf(Ln,wrl[96+il],b3);
      }
      __syncthreads();
      if (tid<128){
        int r=tid>>5, il=tid&31;
        float s=fpart[r*32+il]+fpart[128+r*32+il]+fpart[256+r*32+il]+fpart[384+r*32+il];
        st_agt(ws+OFF_FWD+(size_t)(b<<10)+(r<<8)+(rc<<5)+il, s);
      }
      float* bwd=ws+OFF_BWD+(size_t)(b<<10);
      atomicAdd(&bwd[j],b0); atomicAdd(&bwd[256+j],b1);
      atomicAdd(&bwd[512+j],b2); atomicAdd(&bwd[768+j],b3);
    } else if (bid < 144){
      int b=bid-128;
      float ga=ld_agt(ws+OFF_SCL+b*4), gw=ld_agt(ws+OFF_SCL+b*4+1), sA=ld_agt(ws+OFF_SCL+b*4+2);
      float sww=gw*(ga*sA+(1.f-ga));
      float2 er = ld2_agt(ws+OFF_ERS+(b<<6)+(l32<<1));
      float2 wvv= ld2_agt(ws+OFF_WVC+(b<<6)+(l32<<1));
      float* memb=ws+OFF_MEM+(size_t)b*16384;
      for (int i=0;i<32;++i){
        int n=(wv<<6)+(i<<1)+half;
        float wwn=gw*(ga*ld_agt(ws+OFF_ALC+(b<<8)+n)+(1.f-ga)*ld_agt(ws+OFF_CW+(b<<8)+n));
        float2 v=ld2_agt(memb+(n<<6)+(l32<<1));
        v.x=v.x*(1.f-wwn*er.x)+wwn*wvv.x;
        v.y=v.y*(1.f-wwn*er.y)+wwn*wvv.y;
        st2_agt(memb+(n<<6)+(l32<<1), v);
        float s2=hredsum32(v.x*v.x+v.y*v.y);
        if (l32==0){
          st_agt(ws+OFF_NRM+(b<<8)+n, s2);
          st_agt(ws+OFF_WW +(b<<8)+n, wwn);
          float po=ld_agt(ws+OFF_PRC+(size_t)(t&1)*4096+(b<<8)+n);
          st_agt(ws+OFF_PRC+(size_t)((t+1)&1)*4096+(b<<8)+n, (1.f-sww)*po+wwn);
        }
      }
    }
    ep++; gbar(flg, rel, ep, bid);

    // ====== P3: read heads (bid=16*r+b, XCD-pinned, mem cached in regs) ======
    if (bid < 64){
      int b=bid&15, r=bid>>4;
      float* knl=smem; float* sims=smem+64; float* wrs=smem+320; float* pt=smem+576; float* red=smem+1088;
      if (wv==0) knl[lane]=ld_agt(ws+OFF_KNR+(b<<8)+(r<<6)+lane);
      __syncthreads();
      const float* memb=ws+OFF_MEM+(size_t)b*16384;
      float2 mv[32];
      #pragma unroll 4
      for (int i=0;i<32;++i){
        int n=(wv<<6)+(i<<1)+half;
        float2 v=ld2_agt(memb+(n<<6)+(l32<<1));
        mv[i]=v;
        float d=hredsum32(v.x*knl[l32<<1]+v.y*knl[(l32<<1)+1]);
        if (l32==0) sims[n]=d/(sqrtf(ld_agt(ws+OFF_NRM+(b<<8)+n))+1e-6f);
      }
      __syncthreads();
      float s=sims[tid];
      float mx=bredmax(s,red); float e=expf(s-mx); float sm=bredsum(e,red);
      float cr=e/sm;
      float p0=ld_agt(ws+OFF_PI+b*16+r*3), p1=ld_agt(ws+OFF_PI+b*16+r*3+1), p2=ld_agt(ws+OFF_PI+b*16+r*3+2);
      float wr=p0*ld_sys(ws+OFF_BWD+(size_t)(b<<10)+(r<<8)+tid) + p1*cr
             + p2*ld_agt(ws+OFF_FWD+(size_t)(b<<10)+(r<<8)+tid);
      st_agt(ws+OFF_WR+(size_t)(b<<10)+(r<<8)+tid, wr);
      wrs[tid]=wr;
      __syncthreads();
      float ax=0.f, ay=0.f;
      #pragma unroll 4
      for (int i=0;i<32;++i){
        int n=(wv<<6)+(i<<1)+half;
        float w=wrs[n];
        ax=fmaf(w,mv[i].x,ax); ay=fmaf(w,mv[i].y,ay);
      }
      int slot=(wv<<1)+half;
      pt[slot*64+(l32<<1)]=ax; pt[slot*64+(l32<<1)+1]=ay;
      __syncthreads();
      if (tid<64){
        float sm2=0.f;
        #pragma unroll
        for (int s2=0;s2<8;++s2) sm2+=pt[s2*64+tid];
        st_sys(ws+OFF_RV+(b<<8)+(r<<6)+tid, sm2);
      }
    }
    ep++; gbar(flg, rel, ep, bid);

    // ====== P4: gates-rv(t+1) add (0..63) | y output (64..71) ======
    if (bid < 64){
      if (t < 255){
        stage_rv_sys(sx, ws+OFF_RV);
        __syncthreads();
        sgemm_core(sred, sx, Wx+(size_t)264*2048, 2048, (bid<<5)+(tid&31), 32);
        __syncthreads();
        for (int o=tid;o<512;o+=NT){
          int b=o>>5, c=o&31;
          atomicAdd(gp_nxt + (size_t)(b<<11) + (bid<<5) + c, SRED8(o));
        }
      }
    } else if (bid < 72){
      stage_rv_sys(sx, ws+OFF_RV);
      __syncthreads();
      int cbase=(bid-64)<<5;
      sgemm_core(sred, sx, Wr, 256, cbase+(tid&31), 32);
      __syncthreads();
      for (int o=tid;o<512;o+=NT){
        int b=o>>5, c=o&31;
        out[((size_t)((b<<8)+t)<<8)+cbase+c] = ld_sys(ws+OFF_YH+(b<<8)+cbase+c) + SRED8(o);
      }
    }
    ep++; gbar(flg, rel, ep, bid);
  }
}

extern "C" void kernel_launch(void* const* d_in, const int* in_sizes, int n_in,
                              void* d_out, int out_size, void* d_ws, size_t ws_size,
                              hipStream_t stream) {
  (void)in_sizes; (void)out_size;
  if (n_in < 9) return;
  const float* xin = (const float*)d_in[0];
  const float* Wx  = (const float*)d_in[1];
  const float* Wh  = (const float*)d_in[2];
  const float* bl  = (const float*)d_in[3];
  const float* Wxi = (const float*)d_in[4];
  const float* bxi = (const float*)d_in[5];
  const float* Wy  = (const float*)d_in[6];
  const float* Wr  = (const float*)d_in[7];
  const float* by  = (const float*)d_in[8];
  float* out = (float*)d_out;
  float* ws  = (float*)d_ws;
  if (ws_size < WS_TOTAL*sizeof(float)) return;

  hipLaunchKernelGGL(k_zero, dim3(512), dim3(256), 0, stream, ws);
  hipLaunchKernelGGL(k_dnc, dim3(NB), dim3(NT), 0, stream,
                     xin, Wx, Wh, bl, Wxi, bxi, Wy, Wr, by, out, ws);
}

// Round 9
// 28227.539 us; speedup vs baseline: 1.6565x; 1.6565x over previous
//
#include <hip/hip_runtime.h>
#include <cstddef>

#define DEV __device__ __forceinline__

// ---- dims: B=16 S=256 IN_DIM=264 H=512 4H=2048 XI=471 N=256 M=64 R=4 OUT=256
constexpr int S_ = 256;
constexpr int NB = 256;
constexpr int NT = 256;

// R8 post-mortem: serial memory-op chain x latency dominates; global sync and
// cross-XCD LLC trips are the chain. R9: batches are independent -> 16 crews
// of 16 blocks, crew b pinned to XCD b%8 (bid = b%8 + 8*(2*ci+s), placement
// rule proven R6-R8). NO global barriers. All per-batch state agent-scope
// (XCD-local), weights read-only plain-cached, link rows block-private
// (L1-resident). 5 per-crew barriers/step via XCD-local flags.
// BWD uses the R7-proven sys-zero + device-atomicAdd + sys-read combo.

// per-batch region offsets (floats), region stride PB, base ws + b*PB
constexpr size_t bH   = 0;       // 2x512 h ping-pong [agent]
constexpr size_t bC   = 1024;    // 512 LSTM c        [private: block ci=j/32]
constexpr size_t bXI  = 1536;    // 512 (471 used)    [agent]
constexpr size_t bKNR = 2048;    // 256 [agent]
constexpr size_t bALC = 2304;    // 256 [agent]
constexpr size_t bCW  = 2560;    // 256 [agent]
constexpr size_t bWW  = 2816;    // 256 [agent]
constexpr size_t bNRM = 3072;    // 256 [agent]
constexpr size_t bUSG = 3328;    // 256 [private: ctrl block]
constexpr size_t bRV  = 3584;    // 256 [agent]
constexpr size_t bYH  = 3840;    // 256 [agent]
constexpr size_t bSCL = 4096;    // 32  [agent]
constexpr size_t bPI  = 4128;    // 32  [agent]
constexpr size_t bERS = 4160;    // 64  [agent]
constexpr size_t bWVC = 4224;    // 64  [agent]
constexpr size_t bPRC = 4288;    // 2x256 [agent]
constexpr size_t bWR  = 4800;    // 4x256 [agent]
constexpr size_t bFWD = 5824;    // 4x256 [agent]
constexpr size_t bBWD = 6848;    // 4x256 [sys + device atomicAdd]
constexpr size_t bFLG = 7872;    // 16 crew arrival flags x 32
constexpr size_t bREL = 8384;    // release line
constexpr size_t bMEM = 8448;    // 256x64 [agent]
constexpr size_t bLNK = 24832;   // 256x256 [private: block ci owns rows 16ci..]
constexpr size_t PB   = 90624;
constexpr size_t WS_TOTAL = PB*16;   // ~5.80 MB (< proven 6.04 MB)

typedef unsigned long long u64_;
union F2U { u64_ u; float2 f; };
DEV float2 ld2_agt(const float* p){ F2U c; c.u=__hip_atomic_load((const u64_*)p,__ATOMIC_RELAXED,__HIP_MEMORY_SCOPE_AGENT); return c.f; }
DEV void   st2_agt(float* p, float2 v){ F2U c; c.f=v; __hip_atomic_store((u64_*)p,c.u,__ATOMIC_RELAXED,__HIP_MEMORY_SCOPE_AGENT); }
DEV float  ld_agt(const float* p){ return __hip_atomic_load((float*)p,__ATOMIC_RELAXED,__HIP_MEMORY_SCOPE_AGENT); }
DEV void   st_agt(float* p,float v){ __hip_atomic_store(p,v,__ATOMIC_RELAXED,__HIP_MEMORY_SCOPE_AGENT); }
DEV float  ld_sys(const float* p){ return __hip_atomic_load((float*)p,__ATOMIC_RELAXED,__HIP_MEMORY_SCOPE_SYSTEM); }
DEV void   st_sys(float* p,float v){ __hip_atomic_store(p,v,__ATOMIC_RELAXED,__HIP_MEMORY_SCOPE_SYSTEM); }

DEV float sigm(float x){ return 1.0f/(1.0f+expf(-x)); }
DEV float oneplus_(float x){ float sp = (x>20.0f)? x : log1pf(expf(x)); return 1.0f+sp; }

DEV float wredsum(float v){
  #pragma unroll
  for (int o=32;o>0;o>>=1) v += __shfl_xor(v,o);
  return v;
}
DEV float hredsum32(float v){
  #pragma unroll
  for (int o=16;o>0;o>>=1) v += __shfl_xor(v,o);
  return v;
}
DEV float wredmax(float v){
  #pragma unroll
  for (int o=32;o>0;o>>=1) v = fmaxf(v,__shfl_xor(v,o));
  return v;
}
DEV float bredsum(float v, float* red){
  v = wredsum(v);
  if ((threadIdx.x&63)==0) red[threadIdx.x>>6]=v;
  __syncthreads();
  float r = red[0]+red[1]+red[2]+red[3];
  __syncthreads();
  return r;
}
DEV float bredmax(float v, float* red){
  v = wredmax(v);
  if ((threadIdx.x&63)==0) red[threadIdx.x>>6]=v;
  __syncthreads();
  float r = fmaxf(fmaxf(red[0],red[1]),fmaxf(red[2],red[3]));
  __syncthreads();
  return r;
}

// crew barrier: 16 blocks, same XCD, agent-scope flags in local L2.
// __syncthreads drains vmcnt(0) per wave -> prior stores visible (R4..R8).
DEV void cbar(float* wsb, unsigned ep, int ci){
  unsigned* flg = (unsigned*)(wsb + bFLG);
  unsigned* rel = (unsigned*)(wsb + bREL);
  __syncthreads();
  const int tid = threadIdx.x;
  if (ci == 0){
    if (tid < 64){
      if (tid == 0)
        __hip_atomic_store(flg, ep, __ATOMIC_RELAXED, __HIP_MEMORY_SCOPE_AGENT);
      bool ok;
      do {
        unsigned v = (tid<16) ? __hip_atomic_load(flg + (size_t)tid*32,
                        __ATOMIC_RELAXED, __HIP_MEMORY_SCOPE_AGENT) : ep;
        ok = __all(v >= ep);
        if (!ok) __builtin_amdgcn_s_sleep(1);
      } while (!ok);
      if (tid == 0)
        __hip_atomic_store(rel, ep, __ATOMIC_RELAXED, __HIP_MEMORY_SCOPE_AGENT);
    }
  } else {
    if (tid == 0){
      __hip_atomic_store(flg + (size_t)ci*32, ep, __ATOMIC_RELAXED, __HIP_MEMORY_SCOPE_AGENT);
      while (__hip_atomic_load(rel, __ATOMIC_RELAXED, __HIP_MEMORY_SCOPE_AGENT) < ep)
        __builtin_amdgcn_s_sleep(1);
    }
  }
  __syncthreads();
}

__global__ void k_zero(float* __restrict__ ws){
  size_t i = (size_t)blockIdx.x*blockDim.x + threadIdx.x;
  size_t st = (size_t)gridDim.x*blockDim.x;
  for (; i<WS_TOTAL; i+=st) ws[i]=0.0f;
}

__global__ __launch_bounds__(NT, 2) void k_dnc(
    const float* __restrict__ xin, const float* __restrict__ Wx,
    const float* __restrict__ Wh,  const float* __restrict__ bl,
    const float* __restrict__ Wxi, const float* __restrict__ bxi,
    const float* __restrict__ Wy,  const float* __restrict__ Wr,
    const float* __restrict__ by,  float* __restrict__ out,
    float* __restrict__ ws)
{
  __shared__ float smem[14336];   // 57 KB (forces low blocks/CU; grid==CU count)
  const int tid  = threadIdx.x;
  const int bid  = blockIdx.x;
  const int lane = tid & 63, wv = tid >> 6;
  // crew mapping: XCD x = bid%8; q = bid/8; s = q&1; ci = q>>1; batch = x+8s
  const int x  = bid & 7;
  const int q  = bid >> 3;
  const int s  = q & 1;
  const int ci = q >> 1;
  const int b  = x + (s<<3);
  float* wsb = ws + (size_t)b*PB;
  unsigned ep = 0;

  for (int t=0; t<S_; ++t){
    // ================= A: gates GEMM + LSTM + y(t-1) finalize =================
    {
      float* sact = smem;          // 1032 (pad 1040)
      float* sred = smem + 1040;   // 8x128
      float* gall = smem + 2064;   // 128
      float* ysum = smem + 2192;   // 256
      const float* hrd = wsb + bH + (size_t)(t&1)*512;
      float* hwr = wsb + bH + (size_t)((t+1)&1)*512;
      for (int e=tid; e<1032; e+=NT){
        float v;
        if (e < 264)      v = xin[((size_t)(b*256+t))*264 + e];
        else if (e < 520) v = ld_agt(wsb + bRV + (e-264));
        else              v = ld_agt(hrd + (e-520));
        sact[e] = v;
      }
      __syncthreads();
      if (t > 0){  // y(t-1) = YH + rv(t-1) @ Wr ; rv staged in sact[264..519]
        int ks2 = tid>>4, cc = tid&15;
        int yc = (ci<<4) + cc;
        float a = 0.f;
        const float* wp = Wr + (size_t)(ks2*16)*256 + yc;
        const float* rp = sact + 264 + ks2*16;
        #pragma unroll
        for (int k=0;k<16;++k) a = fmaf(rp[k], wp[(size_t)k*256], a);
        ysum[ks2*16 + cc] = a;
        __syncthreads();
        if (tid < 16){
          float sm = 0.f;
          #pragma unroll
          for (int p=0;p<16;++p) sm += ysum[p*16 + tid];
          int yc2 = (ci<<4) + tid;
          out[((size_t)(b*256 + (t-1)))*256 + yc2] = ld_agt(wsb+bYH+yc2) + sm;
        }
        __syncthreads();
      }
      // gates GEMM: 128 cols (4 gates x 32 h-elems of this block), k=1032, 8-way ksplit
      {
        const int colq = tid & 31;
        const int ksA  = tid >> 5;
        const int g    = colq >> 3;
        const int col  = (g<<9) + (ci<<5) + ((colq&7)<<2);
        float4 acc; acc.x=0.f; acc.y=0.f; acc.z=0.f; acc.w=0.f;
        const float4* wp; const float* xp; int kn;
        if (ksA < 4){
          int k0 = ksA*130; kn = 130;
          wp = (const float4*)(Wx + (size_t)k0*2048 + col);
          xp = sact + k0;
        } else {
          int k0 = (ksA-4)*128; kn = 128;
          wp = (const float4*)(Wh + (size_t)k0*2048 + col);
          xp = sact + 520 + k0;
        }
        #pragma unroll 8
        for (int k=0;k<kn;++k){
          float4 w = wp[(size_t)k*512];
          float xv = xp[k];
          acc.x=fmaf(w.x,xv,acc.x); acc.y=fmaf(w.y,xv,acc.y);
          acc.z=fmaf(w.z,xv,acc.z); acc.w=fmaf(w.w,xv,acc.w);
        }
        *(float4*)(sred + ksA*128 + (colq<<2)) = acc;
      }
      __syncthreads();
      if (tid < 128){
        int gg = tid>>5, cc = (ci<<5) + (tid&31);
        float sm = bl[(gg<<9)+cc];
        #pragma unroll
        for (int p=0;p<8;++p) sm += sred[(p<<7) + tid];
        gall[tid] = sm;
      }
      __syncthreads();
      if (tid < 32){
        int j = (ci<<5) + tid;
        float gi=gall[tid], gf=gall[32+tid], gg2=gall[64+tid], go=gall[96+tid];
        float co = wsb[bC + j];          // private (same CU every step)
        float cn = sigm(gf)*co + sigm(gi)*tanhf(gg2);
        float hn = sigm(go)*tanhf(cn);
        wsb[bC + j] = cn;
        st_agt(hwr + j, hn);
      }
    }
    ep++; cbar(wsb, ep, ci);

    // ================= B: xi = h@Wxi + bxi ; YH = h@Wy + by =================
    {
      float* shh = smem;         // 512
      float* sp  = smem + 512;   // 8x30
      float* syh = smem + 768;   // 16x16
      const float* hcur = wsb + bH + (size_t)((t+1)&1)*512;
      for (int e=tid; e<512; e+=NT) shh[e] = ld_agt(hcur + e);
      __syncthreads();
      const int nc = (ci<15) ? 30 : 21;
      if (tid < 240){
        int ks = tid/30, cc = tid%30;
        if (cc < nc){
          int col = ci*30 + cc;
          float a = 0.f;
          const float* wp = Wxi + (size_t)(ks*64)*471 + col;
          const float* hp = shh + ks*64;
          #pragma unroll 8
          for (int k=0;k<64;++k) a = fmaf(hp[k], wp[(size_t)k*471], a);
          sp[ks*30 + cc] = a;
        }
      }
      {
        int ks = tid>>4, cc = tid&15;
        int col = (ci<<4) + cc;
        float a = 0.f;
        const float* wp = Wy + (size_t)(ks*32)*256 + col;
        const float* hp = shh + ks*32;
        #pragma unroll 8
        for (int k=0;k<32;++k) a = fmaf(hp[k], wp[(size_t)k*256], a);
        syh[ks*16 + cc] = a;
      }
      __syncthreads();
      if (tid < nc){
        float sm = bxi[ci*30 + tid];
        #pragma unroll
        for (int p=0;p<8;++p) sm += sp[p*30 + tid];
        st_agt(wsb + bXI + ci*30 + tid, sm);
      }
      if (tid < 16){
        float sm = by[(ci<<4) + tid];
        #pragma unroll
        for (int p=0;p<16;++p) sm += syh[p*16 + tid];
        st_agt(wsb + bYH + (ci<<4) + tid, sm);
      }
    }
    ep++; cbar(wsb, ep, ci);

    // ================= C: ctrl(ci0) | content(ci1) | zero BWD(ci2) =================
    if (ci == 0){
      float* xv = smem; float* uu = smem+512; float* sa = smem+768;
      float* sb = smem+1024; float* red = smem+1280;
      if (tid < 240){
        float2 v = ld2_agt(wsb + bXI + (tid<<1));
        xv[tid<<1]=v.x; xv[(tid<<1)+1]=v.y;
      }
      __syncthreads();
      int n = tid;
      float f0=sigm(xv[453]), f1=sigm(xv[454]), f2v=sigm(xv[455]), f3=sigm(xv[456]);
      const float* wrb = wsb + bWR;
      float psi=(1.f-f0*ld_agt(wrb+n))*(1.f-f1*ld_agt(wrb+256+n))
               *(1.f-f2v*ld_agt(wrb+512+n))*(1.f-f3*ld_agt(wrb+768+n));
      float uo=wsb[bUSG+n];
      float wwp=ld_agt(wsb+bWW+n);
      float un=(uo+wwp-uo*wwp)*psi;
      uu[n]=un; wsb[bUSG+n]=un;
      __syncthreads();
      int rk=0;
      #pragma unroll 8
      for (int j=0;j<256;++j){
        float uj=uu[j];
        rk += (uj<un)||(uj==un && j<n);
      }
      sa[rk]=un;
      __syncthreads();
      float* cur=sa; float* nxt=sb;
      for (int off=1;off<256;off<<=1){
        float v=cur[n]; if (n>=off) v*=cur[n-off];
        nxt[n]=v;
        __syncthreads();
        float* tmp=cur; cur=nxt; nxt=tmp;
      }
      float pe = rk ? cur[rk-1] : 1.f;
      float al = (1.f-un)*pe;
      st_agt(wsb+bALC+n, al);
      float sumA = bredsum(al, red);
      if (tid==0){
        st_agt(wsb+bSCL+0, sigm(xv[457]));
        st_agt(wsb+bSCL+1, sigm(xv[458]));
        st_agt(wsb+bSCL+2, sumA);
      }
      {
        int r=tid>>6, m=tid&63;
        float kv=xv[(r<<6)+m];
        float s2=wredsum(kv*kv);
        float br=oneplus_(xv[256+r]);
        st_agt(wsb+bKNR+tid, kv*br/(sqrtf(s2)+1e-6f));
      }
      if (tid<4){
        float p0=xv[459+tid*3], p1=xv[460+tid*3], p2=xv[461+tid*3];
        float mx=fmaxf(p0,fmaxf(p1,p2));
        float e0=expf(p0-mx), e1=expf(p1-mx), e2=expf(p2-mx);
        float sm=e0+e1+e2;
        st_agt(wsb+bPI+tid*3+0, e0/sm);
        st_agt(wsb+bPI+tid*3+1, e1/sm);
        st_agt(wsb+bPI+tid*3+2, e2/sm);
      }
      if (tid<64){
        st_agt(wsb+bERS+tid, sigm(xv[325+tid]));
        st_agt(wsb+bWVC+tid, xv[389+tid]);
      }
    } else if (ci == 1){
      float* knw=smem; float* sims=smem+64; float* red=smem+320;
      const int half = lane>>5, l32 = lane&31;
      if (wv==0){
        float kv=ld_agt(wsb+bXI+260+lane);
        float s2=wredsum(kv*kv);
        float bw_=oneplus_(ld_agt(wsb+bXI+324));
        knw[lane]=kv*bw_/(sqrtf(s2)+1e-6f);
      }
      __syncthreads();
      const float* memb=wsb+bMEM;
      for (int i2=0;i2<32;++i2){
        int n=(wv<<6)+(i2<<1)+half;
        float2 v=ld2_agt(memb+(n<<6)+(l32<<1));
        float d=hredsum32(v.x*knw[l32<<1]+v.y*knw[(l32<<1)+1]);
        if (l32==0) sims[n]=d/(sqrtf(ld_agt(wsb+bNRM+n))+1e-6f);
      }
      __syncthreads();
      float sv=sims[tid];
      float mx=bredmax(sv,red); float e=expf(sv-mx); float sm=bredsum(e,red);
      st_agt(wsb+bCW+tid, e/sm);
    } else if (ci == 2){
      for (int e=tid;e<1024;e+=NT) st_sys(wsb+bBWD+e, 0.f);
    }
    ep++; cbar(wsb, ep, ci);

    // ================= D: link rows 16ci.. + fwd/bwd + mem/nrm/prec =================
    {
      float* wwl   = smem;         // 256 w_w per slot
      float* wrl   = smem + 256;   // 4x16
      float* fpart = smem + 320;   // 4wv x 4r x 16
      float* sscl  = smem + 576;   // 4
      const int ri = ci<<4;
      if (tid < 3) sscl[tid] = ld_agt(wsb+bSCL+tid);
      __syncthreads();
      float ga = sscl[0], gw = sscl[1], sA = sscl[2];
      float sww = gw*(ga*sA + (1.f-ga));
      int j = tid;
      float wj = gw*(ga*ld_agt(wsb+bALC+j) + (1.f-ga)*ld_agt(wsb+bCW+j));
      wwl[j] = wj;
      if (ci == 1) st_agt(wsb+bWW+j, wj);
      float pj = ld_agt(wsb+bPRC + (size_t)(t&1)*256 + j);
      if (ci == 0) st_agt(wsb+bPRC + (size_t)((t+1)&1)*256 + j, (1.f-sww)*pj + wj);
      const float* wrb = wsb + bWR;
      float wr0=ld_agt(wrb+j), wr1=ld_agt(wrb+256+j),
            wr2=ld_agt(wrb+512+j), wr3=ld_agt(wrb+768+j);
      if (tid < 64) wrl[(tid>>4)*16 + (tid&15)] = ld_agt(wrb + ((size_t)(tid>>4)<<8) + ri + (tid&15));
      __syncthreads();
      float b0=0.f,b1=0.f,b2=0.f,b3=0.f;
      float* lrow = wsb + bLNK + (size_t)ri*256;   // private, L1-resident
      for (int il=0; il<16; ++il){
        int irow = ri + il;
        float Lo = lrow[il*256 + j];
        float wi = wwl[irow];
        float Ln = (1.f - wi - wj)*Lo + wi*pj;
        if (irow == j) Ln = 0.f;
        lrow[il*256 + j] = Ln;
        float s0=wredsum(Ln*wr0), s1=wredsum(Ln*wr1), s2=wredsum(Ln*wr2), s3=wredsum(Ln*wr3);
        if (lane==0){
          fpart[wv*64 + il]      = s0;
          fpart[wv*64 + 16 + il] = s1;
          fpart[wv*64 + 32 + il] = s2;
          fpart[wv*64 + 48 + il] = s3;
        }
        b0=fmaf(Ln, wrl[il],    b0);
        b1=fmaf(Ln, wrl[16+il], b1);
        b2=fmaf(Ln, wrl[32+il], b2);
        b3=fmaf(Ln, wrl[48+il], b3);
      }
      __syncthreads();
      if (tid < 64){
        int r = tid>>4, il = tid&15;
        float sm = fpart[r*16+il] + fpart[64+r*16+il] + fpart[128+r*16+il] + fpart[192+r*16+il];
        st_agt(wsb+bFWD + ((size_t)r<<8) + ri + il, sm);
      }
      float* bwd = wsb + bBWD;
      atomicAdd(&bwd[j], b0);      atomicAdd(&bwd[256+j], b1);
      atomicAdd(&bwd[512+j], b2);  atomicAdd(&bwd[768+j], b3);
      // mem update rows ri..ri+15
      {
        int row2 = tid>>5, c2 = tid&31;
        float2 er  = ld2_agt(wsb+bERS + (c2<<1));
        float2 wv2 = ld2_agt(wsb+bWVC + (c2<<1));
        #pragma unroll
        for (int it=0; it<2; ++it){
          int row = ri + row2 + it*8;
          float wwn = wwl[row];
          float2 v = ld2_agt(wsb+bMEM + ((size_t)row<<6) + (c2<<1));
          v.x = v.x*(1.f - wwn*er.x) + wwn*wv2.x;
          v.y = v.y*(1.f - wwn*er.y) + wwn*wv2.y;
          st2_agt(wsb+bMEM + ((size_t)row<<6) + (c2<<1), v);
          float s2 = hredsum32(v.x*v.x + v.y*v.y);
          if (c2==0) st_agt(wsb+bNRM+row, s2);
        }
      }
    }
    ep++; cbar(wsb, ep, ci);

    // ================= E: read heads (ci<4: head r=ci) =================
    if (ci < 4){
      int r = ci;
      float* knl=smem; float* sims=smem+64; float* wrs=smem+320;
      float* part=smem+576; float* red=smem+832;
      if (wv==0) knl[lane]=ld_agt(wsb+bKNR+(r<<6)+lane);
      __syncthreads();
      const float* memb = wsb + bMEM;
      {
        int row2 = tid>>5, c2 = tid&31;
        for (int it=0; it<32; ++it){
          int n = row2 + it*8;
          float2 v = ld2_agt(memb + ((size_t)n<<6) + (c2<<1));
          float d = hredsum32(v.x*knl[c2<<1] + v.y*knl[(c2<<1)+1]);
          if (c2==0) sims[n] = d/(sqrtf(ld_agt(wsb+bNRM+n))+1e-6f);
        }
      }
      __syncthreads();
      float sv=sims[tid];
      float mx=bredmax(sv,red); float e=expf(sv-mx); float sm=bredsum(e,red);
      float cr=e/sm;
      float p0=ld_agt(wsb+bPI+r*3), p1=ld_agt(wsb+bPI+r*3+1), p2=ld_agt(wsb+bPI+r*3+2);
      float wr = p0*ld_sys(wsb+bBWD+((size_t)r<<8)+tid) + p1*cr
               + p2*ld_agt(wsb+bFWD+((size_t)r<<8)+tid);
      st_agt(wsb+bWR+((size_t)r<<8)+tid, wr);
      wrs[tid]=wr;
      __syncthreads();
      {
        int m = tid&63, ksn = tid>>6;
        float a=0.f;
        #pragma unroll 8
        for (int n0=0;n0<64;++n0){
          int n = (ksn<<6)+n0;
          a = fmaf(wrs[n], ld_agt(memb + ((size_t)n<<6) + m), a);
        }
        part[(ksn<<6)+m]=a;
      }
      __syncthreads();
      if (tid<64)
        st_agt(wsb+bRV+(r<<6)+tid, part[tid]+part[64+tid]+part[128+tid]+part[192+tid]);
    }
    ep++; cbar(wsb, ep, ci);
  }

  // ---- epilogue: y(255) = YH + rv(255) @ Wr ----
  {
    float* srv  = smem;        // 256
    float* ysum = smem + 256;  // 256
    for (int e=tid;e<256;e+=NT) srv[e]=ld_agt(wsb+bRV+e);
    __syncthreads();
    int ks2 = tid>>4, cc = tid&15;
    int yc = (ci<<4) + cc;
    float a = 0.f;
    const float* wp = Wr + (size_t)(ks2*16)*256 + yc;
    const float* rp = srv + ks2*16;
    #pragma unroll
    for (int k=0;k<16;++k) a = fmaf(rp[k], wp[(size_t)k*256], a);
    ysum[ks2*16 + cc] = a;
    __syncthreads();
    if (tid < 16){
      float sm = 0.f;
      #pragma unroll
      for (int p=0;p<16;++p) sm += ysum[p*16 + tid];
      int yc2 = (ci<<4) + tid;
      out[((size_t)(b*256 + 255))*256 + yc2] = ld_agt(wsb+bYH+yc2) + sm;
    }
  }
}

extern "C" void kernel_launch(void* const* d_in, const int* in_sizes, int n_in,
                              void* d_out, int out_size, void* d_ws, size_t ws_size,
                              hipStream_t stream) {
  (void)in_sizes; (void)out_size;
  if (n_in < 9) return;
  const float* xin = (const float*)d_in[0];
  const float* Wx  = (const float*)d_in[1];
  const float* Wh  = (const float*)d_in[2];
  const float* bl  = (const float*)d_in[3];
  const float* Wxi = (const float*)d_in[4];
  const float* bxi = (const float*)d_in[5];
  const float* Wy  = (const float*)d_in[6];
  const float* Wr  = (const float*)d_in[7];
  const float* by  = (const float*)d_in[8];
  float* out = (float*)d_out;
  float* ws  = (float*)d_ws;
  if (ws_size < WS_TOTAL*sizeof(float)) return;

  hipLaunchKernelGGL(k_zero, dim3(512), dim3(256), 0, stream, ws);
  hipLaunchKernelGGL(k_dnc, dim3(NB), dim3(NT), 0, stream,
                     xin, Wx, Wh, bl, Wxi, bxi, Wy, Wr, by, out, ws);
}

// Round 10
// 23334.912 us; speedup vs baseline: 2.0038x; 1.2097x over previous
//
#include <hip/hip_runtime.h>
#include <cstddef>

#define DEV __device__ __forceinline__

// ---- dims: B=16 S=256 IN_DIM=264 H=512 4H=2048 XI=471 N=256 M=64 R=4 OUT=256
constexpr int S_ = 256;
constexpr int NB = 256;
constexpr int NT = 256;

// R9 post-mortem: FETCH 11.1GB (43MB/step) = phase-A weight stream from
// LLC/HBM at 455GB/s latency-limited (unroll-8 = too few loads in flight).
// Agent-scope ops post at the LLC (per-XCD L2s not cross-coherent), so the
// "local L2" latency assumption was wrong. R10: (1) software-pipelined
// phase-A k-loop (8xfloat4 double-buffer prefetch, ~16 in flight);
// (2) single-round crew barrier (no master/release hop);
// (3) BWD 16-way atomic contention -> 4 partial slots + 4-load sum in E.
// Crew structure (16 crews x 16 blocks, crew b on XCD b%8, zero global
// barriers) kept from R9 (correct under either scope semantics).

// per-batch region offsets (floats), stride PB, base ws + b*PB
constexpr size_t bH    = 0;       // 2x512 h ping-pong [agent]
constexpr size_t bC    = 1024;    // 512 LSTM c [private: block ci=j/32]
constexpr size_t bXI   = 1536;    // 512 (471 used) [agent]
constexpr size_t bKNR  = 2048;    // 256 [agent]
constexpr size_t bALC  = 2304;    // 256 [agent]
constexpr size_t bCW   = 2560;    // 256 [agent]
constexpr size_t bWW   = 2816;    // 256 [agent]
constexpr size_t bNRM  = 3072;    // 256 [agent]
constexpr size_t bUSG  = 3328;    // 256 [private: ctrl block]
constexpr size_t bRV   = 3584;    // 256 [agent]
constexpr size_t bYH   = 3840;    // 256 [agent]
constexpr size_t bSCL  = 4096;    // 32  [agent]
constexpr size_t bPI   = 4128;    // 32  [agent]
constexpr size_t bERS  = 4160;    // 64  [agent]
constexpr size_t bWVC  = 4224;    // 64  [agent]
constexpr size_t bPRC  = 4288;    // 2x256 [agent]
constexpr size_t bWR   = 4800;    // 4x256 [agent]
constexpr size_t bFWD  = 5824;    // 4x256 [agent]
constexpr size_t bBWDP = 6848;    // 4 slots x 4 heads x 256 [agent zero + dev atomicAdd + agent read]
constexpr size_t bFLG  = 10944;   // 16 crew flags x 32 (1/128B line)
constexpr size_t bMEM  = 11456;   // 256x64 [agent]
constexpr size_t bLNK  = 27840;   // 256x256 [private: block ci owns rows 16ci..]
constexpr size_t PB    = 93376;
constexpr size_t WS_TOTAL = PB*16;   // ~5.98 MB (< proven 6.25 MB)

typedef unsigned long long u64_;
union F2U { u64_ u; float2 f; };
DEV float2 ld2_agt(const float* p){ F2U c; c.u=__hip_atomic_load((const u64_*)p,__ATOMIC_RELAXED,__HIP_MEMORY_SCOPE_AGENT); return c.f; }
DEV void   st2_agt(float* p, float2 v){ F2U c; c.f=v; __hip_atomic_store((u64_*)p,c.u,__ATOMIC_RELAXED,__HIP_MEMORY_SCOPE_AGENT); }
DEV float  ld_agt(const float* p){ return __hip_atomic_load((float*)p,__ATOMIC_RELAXED,__HIP_MEMORY_SCOPE_AGENT); }
DEV void   st_agt(float* p,float v){ __hip_atomic_store(p,v,__ATOMIC_RELAXED,__HIP_MEMORY_SCOPE_AGENT); }

DEV float sigm(float x){ return 1.0f/(1.0f+expf(-x)); }
DEV float oneplus_(float x){ float sp = (x>20.0f)? x : log1pf(expf(x)); return 1.0f+sp; }

DEV float wredsum(float v){
  #pragma unroll
  for (int o=32;o>0;o>>=1) v += __shfl_xor(v,o);
  return v;
}
DEV float hredsum32(float v){
  #pragma unroll
  for (int o=16;o>0;o>>=1) v += __shfl_xor(v,o);
  return v;
}
DEV float wredmax(float v){
  #pragma unroll
  for (int o=32;o>0;o>>=1) v = fmaxf(v,__shfl_xor(v,o));
  return v;
}
DEV float bredsum(float v, float* red){
  v = wredsum(v);
  if ((threadIdx.x&63)==0) red[threadIdx.x>>6]=v;
  __syncthreads();
  float r = red[0]+red[1]+red[2]+red[3];
  __syncthreads();
  return r;
}
DEV float bredmax(float v, float* red){
  v = wredmax(v);
  if ((threadIdx.x&63)==0) red[threadIdx.x>>6]=v;
  __syncthreads();
  float r = fmaxf(fmaxf(red[0],red[1]),fmaxf(red[2],red[3]));
  __syncthreads();
  return r;
}

// crew barrier, single-round: each block posts its flag, all blocks poll all 16.
// __syncthreads drains vmcnt(0) per wave -> prior stores visible (R4..R9).
DEV void cbar(float* wsb, unsigned ep, int ci){
  unsigned* flg = (unsigned*)(wsb + bFLG);
  __syncthreads();
  if (threadIdx.x < 64){
    if (threadIdx.x == 0)
      __hip_atomic_store(flg + (size_t)ci*32, ep, __ATOMIC_RELAXED, __HIP_MEMORY_SCOPE_AGENT);
    const int l = threadIdx.x;
    bool ok;
    do {
      unsigned v = (l<16) ? __hip_atomic_load(flg + (size_t)l*32,
                      __ATOMIC_RELAXED, __HIP_MEMORY_SCOPE_AGENT) : ep;
      ok = __all(v >= ep);
      if (!ok) __builtin_amdgcn_s_sleep(1);
    } while (!ok);
  }
  __syncthreads();
}

__global__ void k_zero(float* __restrict__ ws){
  size_t i = (size_t)blockIdx.x*blockDim.x + threadIdx.x;
  size_t st = (size_t)gridDim.x*blockDim.x;
  for (; i<WS_TOTAL; i+=st) ws[i]=0.0f;
}

__global__ __launch_bounds__(NT, 2) void k_dnc(
    const float* __restrict__ xin, const float* __restrict__ Wx,
    const float* __restrict__ Wh,  const float* __restrict__ bl,
    const float* __restrict__ Wxi, const float* __restrict__ bxi,
    const float* __restrict__ Wy,  const float* __restrict__ Wr,
    const float* __restrict__ by,  float* __restrict__ out,
    float* __restrict__ ws)
{
  __shared__ float smem[14336];   // 57 KB
  const int tid  = threadIdx.x;
  const int bid  = blockIdx.x;
  const int lane = tid & 63, wv = tid >> 6;
  // crew mapping: XCD x = bid%8; q = bid/8; s = q&1; ci = q>>1; batch = x+8s
  const int x  = bid & 7;
  const int q  = bid >> 3;
  const int s  = q & 1;
  const int ci = q >> 1;
  const int b  = x + (s<<3);
  float* wsb = ws + (size_t)b*PB;
  unsigned ep = 0;

  for (int t=0; t<S_; ++t){
    // ================= A: gates GEMM (pipelined) + LSTM + y(t-1) =================
    {
      float* sact = smem;          // 1032 (pad 1040)
      float* sred = smem + 1040;   // 8x128
      float* gall = smem + 2064;   // 128
      float* ysum = smem + 2192;   // 256
      const float* hrd = wsb + bH + (size_t)(t&1)*512;
      float* hwr = wsb + bH + (size_t)((t+1)&1)*512;
      for (int e=tid; e<1032; e+=NT){
        float v;
        if (e < 264)      v = xin[((size_t)(b*256+t))*264 + e];
        else if (e < 520) v = ld_agt(wsb + bRV + (e-264));
        else              v = ld_agt(hrd + (e-520));
        sact[e] = v;
      }
      __syncthreads();
      if (t > 0){  // y(t-1) = YH + rv(t-1)@Wr ; rv staged in sact[264..519]
        int ks2 = tid>>4, cc = tid&15;
        int yc = (ci<<4) + cc;
        float a = 0.f;
        const float* wp = Wr + (size_t)(ks2*16)*256 + yc;
        const float* rp = sact + 264 + ks2*16;
        #pragma unroll
        for (int k=0;k<16;++k) a = fmaf(rp[k], wp[(size_t)k*256], a);
        ysum[ks2*16 + cc] = a;
        __syncthreads();
        if (tid < 16){
          float sm = 0.f;
          #pragma unroll
          for (int p=0;p<16;++p) sm += ysum[p*16 + tid];
          int yc2 = (ci<<4) + tid;
          out[((size_t)(b*256 + (t-1)))*256 + yc2] = ld_agt(wsb+bYH+yc2) + sm;
        }
        __syncthreads();
      }
      // gates GEMM: 128 cols, k=1032, 8-way ksplit, SW-pipelined prefetch
      {
        const int colq = tid & 31;
        const int ksA  = tid >> 5;
        const int g    = colq >> 3;
        const int col  = (g<<9) + (ci<<5) + ((colq&7)<<2);
        float4 acc; acc.x=0.f; acc.y=0.f; acc.z=0.f; acc.w=0.f;
        const float4* wp; const float* xp; int kn;
        if (ksA < 4){
          int k0 = ksA*130; kn = 130;
          wp = (const float4*)(Wx + (size_t)k0*2048 + col);
          xp = sact + k0;
        } else {
          int k0 = (ksA-4)*128; kn = 128;
          wp = (const float4*)(Wh + (size_t)k0*2048 + col);
          xp = sact + 520 + k0;
        }
        const int nch = (kn+7)>>3;
        float4 buf[8];
        #pragma unroll
        for (int i=0;i<8;++i){
          int kk = (i<kn)? i : kn-1;
          buf[i] = wp[(size_t)kk*512];
        }
        for (int c=0; c<nch; ++c){
          float4 nbuf[8];
          int nb0 = (c+1)<<3;
          #pragma unroll
          for (int i=0;i<8;++i){
            int kk = nb0+i; kk = (kk<kn)? kk : kn-1;
            nbuf[i] = wp[(size_t)kk*512];
          }
          int kb = c<<3;
          #pragma unroll
          for (int i=0;i<8;++i){
            float xv = (kb+i<kn)? xp[kb+i] : 0.f;
            acc.x=fmaf(buf[i].x,xv,acc.x); acc.y=fmaf(buf[i].y,xv,acc.y);
            acc.z=fmaf(buf[i].z,xv,acc.z); acc.w=fmaf(buf[i].w,xv,acc.w);
          }
          #pragma unroll
          for (int i=0;i<8;++i) buf[i]=nbuf[i];
        }
        *(float4*)(sred + ksA*128 + (colq<<2)) = acc;
      }
      __syncthreads();
      if (tid < 128){
        int gg = tid>>5, cc = (ci<<5) + (tid&31);
        float sm = bl[(gg<<9)+cc];
        #pragma unroll
        for (int p=0;p<8;++p) sm += sred[(p<<7) + tid];
        gall[tid] = sm;
      }
      __syncthreads();
      if (tid < 32){
        int j = (ci<<5) + tid;
        float gi=gall[tid], gf=gall[32+tid], gg2=gall[64+tid], go=gall[96+tid];
        float co = wsb[bC + j];          // private (same CU every step)
        float cn = sigm(gf)*co + sigm(gi)*tanhf(gg2);
        float hn = sigm(go)*tanhf(cn);
        wsb[bC + j] = cn;
        st_agt(hwr + j, hn);
      }
    }
    ep++; cbar(wsb, ep, ci);

    // ================= B: xi = h@Wxi + bxi ; YH = h@Wy + by =================
    {
      float* shh = smem;         // 512
      float* sp  = smem + 512;   // 8x30
      float* syh = smem + 768;   // 16x16
      const float* hcur = wsb + bH + (size_t)((t+1)&1)*512;
      for (int e=tid; e<512; e+=NT) shh[e] = ld_agt(hcur + e);
      __syncthreads();
      const int nc = (ci<15) ? 30 : 21;
      if (tid < 240){
        int ks = tid/30, cc = tid%30;
        if (cc < nc){
          int col = ci*30 + cc;
          float a = 0.f;
          const float* wp = Wxi + (size_t)(ks*64)*471 + col;
          const float* hp = shh + ks*64;
          #pragma unroll 8
          for (int k=0;k<64;++k) a = fmaf(hp[k], wp[(size_t)k*471], a);
          sp[ks*30 + cc] = a;
        }
      }
      {
        int ks = tid>>4, cc = tid&15;
        int col = (ci<<4) + cc;
        float a = 0.f;
        const float* wp = Wy + (size_t)(ks*32)*256 + col;
        const float* hp = shh + ks*32;
        #pragma unroll 8
        for (int k=0;k<32;++k) a = fmaf(hp[k], wp[(size_t)k*256], a);
        syh[ks*16 + cc] = a;
      }
      __syncthreads();
      if (tid < nc){
        float sm = bxi[ci*30 + tid];
        #pragma unroll
        for (int p=0;p<8;++p) sm += sp[p*30 + tid];
        st_agt(wsb + bXI + ci*30 + tid, sm);
      }
      if (tid < 16){
        float sm = by[(ci<<4) + tid];
        #pragma unroll
        for (int p=0;p<16;++p) sm += syh[p*16 + tid];
        st_agt(wsb + bYH + (ci<<4) + tid, sm);
      }
    }
    ep++; cbar(wsb, ep, ci);

    // ================= C: ctrl(ci0) | content(ci1) | zero BWDP(ci2) =================
    if (ci == 0){
      float* xv = smem; float* uu = smem+512; float* sa = smem+768;
      float* sb = smem+1024; float* red = smem+1280;
      if (tid < 240){
        float2 v = ld2_agt(wsb + bXI + (tid<<1));
        xv[tid<<1]=v.x; xv[(tid<<1)+1]=v.y;
      }
      __syncthreads();
      int n = tid;
      float f0=sigm(xv[453]), f1=sigm(xv[454]), f2v=sigm(xv[455]), f3=sigm(xv[456]);
      const float* wrb = wsb + bWR;
      float psi=(1.f-f0*ld_agt(wrb+n))*(1.f-f1*ld_agt(wrb+256+n))
               *(1.f-f2v*ld_agt(wrb+512+n))*(1.f-f3*ld_agt(wrb+768+n));
      float uo=wsb[bUSG+n];
      float wwp=ld_agt(wsb+bWW+n);
      float un=(uo+wwp-uo*wwp)*psi;
      uu[n]=un; wsb[bUSG+n]=un;
      __syncthreads();
      int rk=0;
      #pragma unroll 8
      for (int j=0;j<256;++j){
        float uj=uu[j];
        rk += (uj<un)||(uj==un && j<n);
      }
      sa[rk]=un;
      __syncthreads();
      float* cur=sa; float* nxt=sb;
      for (int off=1;off<256;off<<=1){
        float v=cur[n]; if (n>=off) v*=cur[n-off];
        nxt[n]=v;
        __syncthreads();
        float* tmp=cur; cur=nxt; nxt=tmp;
      }
      float pe = rk ? cur[rk-1] : 1.f;
      float al = (1.f-un)*pe;
      st_agt(wsb+bALC+n, al);
      float sumA = bredsum(al, red);
      if (tid==0){
        st_agt(wsb+bSCL+0, sigm(xv[457]));
        st_agt(wsb+bSCL+1, sigm(xv[458]));
        st_agt(wsb+bSCL+2, sumA);
      }
      {
        int r=tid>>6, m=tid&63;
        float kv=xv[(r<<6)+m];
        float s2=wredsum(kv*kv);
        float br=oneplus_(xv[256+r]);
        st_agt(wsb+bKNR+tid, kv*br/(sqrtf(s2)+1e-6f));
      }
      if (tid<4){
        float p0=xv[459+tid*3], p1=xv[460+tid*3], p2=xv[461+tid*3];
        float mx=fmaxf(p0,fmaxf(p1,p2));
        float e0=expf(p0-mx), e1=expf(p1-mx), e2=expf(p2-mx);
        float sm=e0+e1+e2;
        st_agt(wsb+bPI+tid*3+0, e0/sm);
        st_agt(wsb+bPI+tid*3+1, e1/sm);
        st_agt(wsb+bPI+tid*3+2, e2/sm);
      }
      if (tid<64){
        st_agt(wsb+bERS+tid, sigm(xv[325+tid]));
        st_agt(wsb+bWVC+tid, xv[389+tid]);
      }
    } else if (ci == 1){
      float* knw=smem; float* sims=smem+64; float* red=smem+320;
      const int half = lane>>5, l32 = lane&31;
      if (wv==0){
        float kv=ld_agt(wsb+bXI+260+lane);
        float s2=wredsum(kv*kv);
        float bw_=oneplus_(ld_agt(wsb+bXI+324));
        knw[lane]=kv*bw_/(sqrtf(s2)+1e-6f);
      }
      __syncthreads();
      const float* memb=wsb+bMEM;
      for (int i2=0;i2<32;++i2){
        int n=(wv<<6)+(i2<<1)+half;
        float2 v=ld2_agt(memb+(n<<6)+(l32<<1));
        float d=hredsum32(v.x*knw[l32<<1]+v.y*knw[(l32<<1)+1]);
        if (l32==0) sims[n]=d/(sqrtf(ld_agt(wsb+bNRM+n))+1e-6f);
      }
      __syncthreads();
      float sv=sims[tid];
      float mx=bredmax(sv,red); float e=expf(sv-mx); float sm=bredsum(e,red);
      st_agt(wsb+bCW+tid, e/sm);
    } else if (ci == 2){
      for (int e=tid;e<4096;e+=NT) st_agt(wsb+bBWDP+e, 0.f);
    }
    ep++; cbar(wsb, ep, ci);

    // ================= D: link rows 16ci.. + fwd/bwd partials + mem/nrm/prec =================
    {
      float* wwl   = smem;         // 256
      float* wrl   = smem + 256;   // 4x16
      float* fpart = smem + 320;   // 4wv x 4r x 16
      float* sscl  = smem + 576;   // 4
      const int ri = ci<<4;
      if (tid < 3) sscl[tid] = ld_agt(wsb+bSCL+tid);
      __syncthreads();
      float ga = sscl[0], gw = sscl[1], sA = sscl[2];
      float sww = gw*(ga*sA + (1.f-ga));
      int j = tid;
      float wj = gw*(ga*ld_agt(wsb+bALC+j) + (1.f-ga)*ld_agt(wsb+bCW+j));
      wwl[j] = wj;
      if (ci == 1) st_agt(wsb+bWW+j, wj);
      float pj = ld_agt(wsb+bPRC + (size_t)(t&1)*256 + j);
      if (ci == 0) st_agt(wsb+bPRC + (size_t)((t+1)&1)*256 + j, (1.f-sww)*pj + wj);
      const float* wrb = wsb + bWR;
      float wr0=ld_agt(wrb+j), wr1=ld_agt(wrb+256+j),
            wr2=ld_agt(wrb+512+j), wr3=ld_agt(wrb+768+j);
      if (tid < 64) wrl[(tid>>4)*16 + (tid&15)] = ld_agt(wrb + ((size_t)(tid>>4)<<8) + ri + (tid&15));
      __syncthreads();
      float b0=0.f,b1=0.f,b2=0.f,b3=0.f;
      float* lrow = wsb + bLNK + (size_t)ri*256;   // private, L1/L2-resident
      for (int il=0; il<16; ++il){
        int irow = ri + il;
        float Lo = lrow[il*256 + j];
        float wi = wwl[irow];
        float Ln = (1.f - wi - wj)*Lo + wi*pj;
        if (irow == j) Ln = 0.f;
        lrow[il*256 + j] = Ln;
        float s0=wredsum(Ln*wr0), s1=wredsum(Ln*wr1), s2=wredsum(Ln*wr2), s3=wredsum(Ln*wr3);
        if (lane==0){
          fpart[wv*64 + il]      = s0;
          fpart[wv*64 + 16 + il] = s1;
          fpart[wv*64 + 32 + il] = s2;
          fpart[wv*64 + 48 + il] = s3;
        }
        b0=fmaf(Ln, wrl[il],    b0);
        b1=fmaf(Ln, wrl[16+il], b1);
        b2=fmaf(Ln, wrl[32+il], b2);
        b3=fmaf(Ln, wrl[48+il], b3);
      }
      __syncthreads();
      if (tid < 64){
        int r = tid>>4, il = tid&15;
        float sm = fpart[r*16+il] + fpart[64+r*16+il] + fpart[128+r*16+il] + fpart[192+r*16+il];
        st_agt(wsb+bFWD + ((size_t)r<<8) + ri + il, sm);
      }
      float* slot = wsb + bBWDP + (size_t)(ci&3)*1024;   // 4-way contention only
      atomicAdd(&slot[j], b0);      atomicAdd(&slot[256+j], b1);
      atomicAdd(&slot[512+j], b2);  atomicAdd(&slot[768+j], b3);
      // mem update rows ri..ri+15
      {
        int row2 = tid>>5, c2 = tid&31;
        float2 er  = ld2_agt(wsb+bERS + (c2<<1));
        float2 wv2 = ld2_agt(wsb+bWVC + (c2<<1));
        #pragma unroll
        for (int it=0; it<2; ++it){
          int row = ri + row2 + it*8;
          float wwn = wwl[row];
          float2 v = ld2_agt(wsb+bMEM + ((size_t)row<<6) + (c2<<1));
          v.x = v.x*(1.f - wwn*er.x) + wwn*wv2.x;
          v.y = v.y*(1.f - wwn*er.y) + wwn*wv2.y;
          st2_agt(wsb+bMEM + ((size_t)row<<6) + (c2<<1), v);
          float s2 = hredsum32(v.x*v.x + v.y*v.y);
          if (c2==0) st_agt(wsb+bNRM+row, s2);
        }
      }
    }
    ep++; cbar(wsb, ep, ci);

    // ================= E: read heads (ci<4: head r=ci) =================
    if (ci < 4){
      int r = ci;
      float* knl=smem; float* sims=smem+64; float* wrs=smem+320;
      float* part=smem+576; float* red=smem+832;
      if (wv==0) knl[lane]=ld_agt(wsb+bKNR+(r<<6)+lane);
      __syncthreads();
      const float* memb = wsb + bMEM;
      {
        int row2 = tid>>5, c2 = tid&31;
        for (int it=0; it<32; ++it){
          int n = row2 + it*8;
          float2 v = ld2_agt(memb + ((size_t)n<<6) + (c2<<1));
          float d = hredsum32(v.x*knl[c2<<1] + v.y*knl[(c2<<1)+1]);
          if (c2==0) sims[n] = d/(sqrtf(ld_agt(wsb+bNRM+n))+1e-6f);
        }
      }
      __syncthreads();
      float sv=sims[tid];
      float mx=bredmax(sv,red); float e=expf(sv-mx); float sm=bredsum(e,red);
      float cr=e/sm;
      float p0=ld_agt(wsb+bPI+r*3), p1=ld_agt(wsb+bPI+r*3+1), p2=ld_agt(wsb+bPI+r*3+2);
      float bwv = ld_agt(wsb+bBWDP + ((size_t)r<<8) + tid)
                + ld_agt(wsb+bBWDP + 1024 + ((size_t)r<<8) + tid)
                + ld_agt(wsb+bBWDP + 2048 + ((size_t)r<<8) + tid)
                + ld_agt(wsb+bBWDP + 3072 + ((size_t)r<<8) + tid);
      float wr = p0*bwv + p1*cr + p2*ld_agt(wsb+bFWD+((size_t)r<<8)+tid);
      st_agt(wsb+bWR+((size_t)r<<8)+tid, wr);
      wrs[tid]=wr;
      __syncthreads();
      {
        int m = tid&63, ksn = tid>>6;
        float a=0.f;
        #pragma unroll 8
        for (int n0=0;n0<64;++n0){
          int n = (ksn<<6)+n0;
          a = fmaf(wrs[n], ld_agt(memb + ((size_t)n<<6) + m), a);
        }
        part[(ksn<<6)+m]=a;
      }
      __syncthreads();
      if (tid<64)
        st_agt(wsb+bRV+(r<<6)+tid, part[tid]+part[64+tid]+part[128+tid]+part[192+tid]);
    }
    ep++; cbar(wsb, ep, ci);
  }

  // ---- epilogue: y(255) = YH + rv(255) @ Wr ----
  {
    float* srv  = smem;        // 256
    float* ysum = smem + 256;  // 256
    for (int e=tid;e<256;e+=NT) srv[e]=ld_agt(wsb+bRV+e);
    __syncthreads();
    int ks2 = tid>>4, cc = tid&15;
    int yc = (ci<<4) + cc;
    float a = 0.f;
    const float* wp = Wr + (size_t)(ks2*16)*256 + yc;
    const float* rp = srv + ks2*16;
    #pragma unroll
    for (int k=0;k<16;++k) a = fmaf(rp[k], wp[(size_t)k*256], a);
    ysum[ks2*16 + cc] = a;
    __syncthreads();
    if (tid < 16){
      float sm = 0.f;
      #pragma unroll
      for (int p=0;p<16;++p) sm += ysum[p*16 + tid];
      int yc2 = (ci<<4) + tid;
      out[((size_t)(b*256 + 255))*256 + yc2] = ld_agt(wsb+bYH+yc2) + sm;
    }
  }
}

extern "C" void kernel_launch(void* const* d_in, const int* in_sizes, int n_in,
                              void* d_out, int out_size, void* d_ws, size_t ws_size,
                              hipStream_t stream) {
  (void)in_sizes; (void)out_size;
  if (n_in < 9) return;
  const float* xin = (const float*)d_in[0];
  const float* Wx  = (const float*)d_in[1];
  const float* Wh  = (const float*)d_in[2];
  const float* bl  = (const float*)d_in[3];
  const float* Wxi = (const float*)d_in[4];
  const float* bxi = (const float*)d_in[5];
  const float* Wy  = (const float*)d_in[6];
  const float* Wr  = (const float*)d_in[7];
  const float* by  = (const float*)d_in[8];
  float* out = (float*)d_out;
  float* ws  = (float*)d_ws;
  if (ws_size < WS_TOTAL*sizeof(float)) return;

  hipLaunchKernelGGL(k_zero, dim3(512), dim3(256), 0, stream, ws);
  hipLaunchKernelGGL(k_dnc, dim3(NB), dim3(NT), 0, stream,
                     xin, Wx, Wh, bl, Wxi, bxi, Wy, Wr, by, out, ws);
}